// Round 5
// baseline (645.426 us; speedup 1.0000x reference)
//
#include <hip/hip_runtime.h>
#include <hip/hip_fp16.h>
#include <hip/hip_cooperative_groups.h>
#include <cstdint>
#include <cstddef>

namespace cg = cooperative_groups;

typedef _Float16 f16x8 __attribute__((ext_vector_type(8)));
typedef _Float16 f16x4 __attribute__((ext_vector_type(4)));
typedef float    f32x4 __attribute__((ext_vector_type(4)));

#define TC  32   // scan chunk length
#define NCH 32   // chunks per sequence (1024 / TC)

__device__ __forceinline__ float sigmoidf_(float x) { return 1.f / (1.f + __expf(-x)); }

// async global -> LDS, 16 bytes per lane (wave-uniform base + lane*16)
__device__ __forceinline__ void gload_lds16(const _Float16* g, _Float16* l) {
  __builtin_amdgcn_global_load_lds(
      (const __attribute__((address_space(1))) void*)g,
      (__attribute__((address_space(3))) void*)l, 16, 0, 0);
}

// ---------------- fused prep: cast x + transpose W_in/W_x/W_dt/W_out ----------------
__device__ __forceinline__ void t16_body(const float* __restrict__ src,
    _Float16* __restrict__ dst, int R, int C, int Cpad, int bx, int by,
    int tid, float tile[32][33]) {
  int c0 = bx * 32, r0 = by * 32, tx = tid & 31, ty = tid >> 5;  // 32 x 8
  #pragma unroll
  for (int i = 0; i < 4; ++i) {
    int r = r0 + ty + i * 8, c = c0 + tx;
    tile[ty + i * 8][tx] = (r < R && c < C) ? src[(size_t)r * C + c] : 0.f;
  }
  __syncthreads();
  #pragma unroll
  for (int i = 0; i < 4; ++i) {
    int cc = c0 + ty + i * 8, rr = r0 + tx;
    if (cc < Cpad && rr < R) dst[(size_t)cc * R + rr] = (_Float16)tile[tx][ty + i * 8];
  }
}

__global__ __launch_bounds__(256) void k_prep(
    const float* __restrict__ x, _Float16* __restrict__ x16,
    const float* __restrict__ W_in, _Float16* __restrict__ WinT,
    const float* __restrict__ W_x, _Float16* __restrict__ WxT,
    const float* __restrict__ W_dt, _Float16* __restrict__ WdtT,
    const float* __restrict__ W_out, _Float16* __restrict__ WoutT)
{
  __shared__ float tile[32][33];
  const int blk = blockIdx.x, tid = threadIdx.x;
  if (blk < 4096) {                       // cast x: 4096x1024 via float4
    int i = blk * 256 + tid;
    float4 v = ((const float4*)x)[i];
    f16x4 o = {(_Float16)v.x, (_Float16)v.y, (_Float16)v.z, (_Float16)v.w};
    ((f16x4*)x16)[i] = o;
  } else if (blk < 8192) {                // W_in (1024x4096) -> 4096x1024
    int b = blk - 4096;
    t16_body(W_in, WinT, 1024, 4096, 4096, b & 127, b >> 7, tid, tile);
  } else if (blk < 8448) {                // W_x (2048x96) -> 128x2048 (pad)
    int b = blk - 8192;
    t16_body(W_x, WxT, 2048, 96, 128, b & 3, b >> 2, tid, tile);
  } else if (blk < 8576) {                // W_dt (64x2048) -> 2048x64
    int b = blk - 8448;
    t16_body(W_dt, WdtT, 64, 2048, 2048, b & 63, b >> 6, tid, tile);
  } else {                                // W_out (2048x1024) -> 1024x2048
    int b = blk - 8576;
    t16_body(W_out, WoutT, 2048, 1024, 1024, b & 31, b >> 5, tid, tile);
  }
}

// ---------------- MFMA GEMM, BK=64: C(MxN) = A(MxK) * BT(NxK)^T ----------------
// EPI 3: col<2048 -> C16 f16 (xc); col>=2048 -> AUX f16 = silu(v) (z)   (G1)
// EPI 4: C f32 partial, split-K over blockIdx.z (G2 z=4, G4 z=2)
template <int EPI>
__global__ __launch_bounds__(256) void k_gemm_bt(
    const _Float16* __restrict__ A,   // M x K
    const _Float16* __restrict__ BT,  // N x K
    float* __restrict__ C,
    _Float16* __restrict__ C16,
    _Float16* __restrict__ AUX,
    int M, int N, int K)
{
  // 128 rows x 64 cols f16 per tile; row = 128 B; slot s at row r stored at phys s^(r&7)
  __shared__ __align__(16) _Float16 As[128 * 64];
  __shared__ __align__(16) _Float16 Bs[128 * 64];
  const int tid  = threadIdx.x;
  const int lane = tid & 63;
  const int wave = tid >> 6;
  const int wm = (wave >> 1) * 64;
  const int wn = (wave & 1) * 64;
  const int l15 = lane & 15;
  const int q   = lane >> 4;
  const int m0 = blockIdx.y * 128;
  const int n0 = blockIdx.x * 128;

  const int kpb = K / gridDim.z;
  const int k0  = blockIdx.z * kpb;

  const int rch = lane >> 3;
  const int g   = (lane & 7) ^ (rch & 7);
  const _Float16* gA = A  + (size_t)(m0 + wave * 32 + rch) * K + k0 + g * 8;
  const _Float16* gB = BT + (size_t)(n0 + wave * 32 + rch) * K + k0 + g * 8;
  _Float16* lA = As + wave * 32 * 64 + lane * 8;
  _Float16* lB = Bs + wave * 32 * 64 + lane * 8;

  const int sx = l15 & 7;

  f32x4 acc[4][4] = {};

  for (int k = 0; k < kpb; k += 64) {
    #pragma unroll
    for (int c = 0; c < 4; ++c) {
      gload_lds16(gA + (size_t)(c * 8) * K + k, lA + c * 512);
      gload_lds16(gB + (size_t)(c * 8) * K + k, lB + c * 512);
    }
    __syncthreads();
    #pragma unroll
    for (int k32 = 0; k32 < 2; ++k32) {
      f16x8 af[4], bf[4];
      #pragma unroll
      for (int i = 0; i < 4; ++i) {
        af[i] = *(const f16x8*)&As[(wm + i * 16 + l15) * 64 + ((k32 * 4 + q) ^ sx) * 8];
        bf[i] = *(const f16x8*)&Bs[(wn + i * 16 + l15) * 64 + ((k32 * 4 + q) ^ sx) * 8];
      }
      #pragma unroll
      for (int mi = 0; mi < 4; ++mi)
        #pragma unroll
        for (int ni = 0; ni < 4; ++ni)
          acc[mi][ni] = __builtin_amdgcn_mfma_f32_16x16x32_f16(af[mi], bf[ni], acc[mi][ni], 0, 0, 0);
    }
    __syncthreads();
  }

  #pragma unroll
  for (int mi = 0; mi < 4; ++mi) {
    #pragma unroll
    for (int ni = 0; ni < 4; ++ni) {
      int col = n0 + wn + ni * 16 + l15;
      #pragma unroll
      for (int r = 0; r < 4; ++r) {
        int row = m0 + wm + mi * 16 + q * 4 + r;
        float v = acc[mi][ni][r];
        if constexpr (EPI == 3) {
          if (col < 2048) {
            C16[(size_t)row * 2048 + col] = (_Float16)v;
          } else {
            AUX[(size_t)row * 2048 + (col - 2048)] = (_Float16)(v * sigmoidf_(v));
          }
        } else {  // EPI == 4
          C[(size_t)blockIdx.z * M * N + (size_t)row * N + col] = v;
        }
      }
    }
  }
}

// ---------------- G3: dt = softplus( sum_z(Cpart cols0..63) @ W_dt + b_dt ) ----------------
// A staged manually (fused 4-way split-K reduce + f16 cast), padded LDS (stride 72).
__global__ __launch_bounds__(256) void k_g3(
    const float* __restrict__ Cpart,   // 4 x (4096 x 128) partials
    const _Float16* __restrict__ BT,   // WdtT: 2048 x 64
    const float* __restrict__ bias,    // b_dt
    _Float16* __restrict__ AUX)        // dtb: 4096 x 2048
{
  __shared__ __align__(16) _Float16 As2[128 * 72];
  __shared__ __align__(16) _Float16 Bs[128 * 64];
  const int tid  = threadIdx.x;
  const int lane = tid & 63;
  const int wave = tid >> 6;
  const int wm = (wave >> 1) * 64;
  const int wn = (wave & 1) * 64;
  const int l15 = lane & 15;
  const int q   = lane >> 4;
  const int m0 = blockIdx.y * 128;
  const int n0 = blockIdx.x * 128;
  const int PL = 4096 * 128;

  // A: 128 rows x 64 cols = 1024 8-wide units, 4 per thread
  #pragma unroll
  for (int i = 0; i < 4; ++i) {
    int idx = i * 256 + tid;
    int r = idx >> 3, s = idx & 7;
    const float* p = Cpart + (size_t)(m0 + r) * 128 + s * 8;
    f16x8 o;
    #pragma unroll
    for (int j = 0; j < 8; ++j)
      o[j] = (_Float16)(p[j] + p[j + PL] + p[j + 2 * PL] + p[j + 3 * PL]);
    *(f16x8*)&As2[r * 72 + s * 8] = o;
  }
  // B: async swizzled staging (rows n0.., 64 cols)
  const int rch = lane >> 3;
  const int g   = (lane & 7) ^ (rch & 7);
  const _Float16* gB = BT + (size_t)(n0 + wave * 32 + rch) * 64 + g * 8;
  _Float16* lB = Bs + wave * 32 * 64 + lane * 8;
  #pragma unroll
  for (int c = 0; c < 4; ++c)
    gload_lds16(gB + (size_t)(c * 8) * 64, lB + c * 512);
  __syncthreads();

  const int sx = l15 & 7;
  f32x4 acc[4][4] = {};
  #pragma unroll
  for (int k32 = 0; k32 < 2; ++k32) {
    f16x8 af[4], bf[4];
    #pragma unroll
    for (int i = 0; i < 4; ++i) {
      af[i] = *(const f16x8*)&As2[(wm + i * 16 + l15) * 72 + (k32 * 4 + q) * 8];
      bf[i] = *(const f16x8*)&Bs[(wn + i * 16 + l15) * 64 + ((k32 * 4 + q) ^ sx) * 8];
    }
    #pragma unroll
    for (int mi = 0; mi < 4; ++mi)
      #pragma unroll
      for (int ni = 0; ni < 4; ++ni)
        acc[mi][ni] = __builtin_amdgcn_mfma_f32_16x16x32_f16(af[mi], bf[ni], acc[mi][ni], 0, 0, 0);
  }

  #pragma unroll
  for (int mi = 0; mi < 4; ++mi) {
    #pragma unroll
    for (int ni = 0; ni < 4; ++ni) {
      int col = n0 + wn + ni * 16 + l15;
      #pragma unroll
      for (int r = 0; r < 4; ++r) {
        int row = m0 + wm + mi * 16 + q * 4 + r;
        float t = acc[mi][ni][r] + bias[col];
        float sp = (t > 20.f) ? t : log1pf(__expf(t));
        AUX[(size_t)row * 2048 + col] = (_Float16)sp;
      }
    }
  }
}

// ---------------- causal depthwise conv (k=4) + SiLU, f16 in/out ----------------
__global__ __launch_bounds__(256) void k_conv_silu(
    const _Float16* __restrict__ xc, const float* __restrict__ cw,
    const float* __restrict__ cb, _Float16* __restrict__ out)
{
  int idx = blockIdx.x * 256 + threadIdx.x;  // over 4096*2048
  int d = idx & 2047;
  int row = idx >> 11;
  int t = row & 1023;
  const _Float16* p = xc + (size_t)row * 2048 + d;
  float acc = cb[d] + cw[d * 4 + 3] * (float)p[0];
  if (t >= 1) acc += cw[d * 4 + 2] * (float)p[-2048];
  if (t >= 2) acc += cw[d * 4 + 1] * (float)p[-4096];
  if (t >= 3) acc += cw[d * 4 + 0] * (float)p[-6144];
  out[idx] = (_Float16)(acc * sigmoidf_(acc));
}

// ---------------- cooperative selective scan: phases A (local), B (combine), C (emit) ----------------
// grid 512 blocks x 256; block -> (xb: d-group of 512, c: chunk, b: batch), 2 d-halves serially
__global__ __launch_bounds__(256, 2) void k_scan_all(
    const _Float16* __restrict__ dt, const _Float16* __restrict__ u,
    const _Float16* __restrict__ zs, const float* __restrict__ Cpart,
    const float* __restrict__ A_log, const float* __restrict__ Dv,
    float* __restrict__ P, float* __restrict__ S, _Float16* __restrict__ ys)
{
  cg::grid_group gg = cg::this_grid();
  const int tid = threadIdx.x;
  const int blk = blockIdx.x;           // 0..511
  const int xb = blk & 3;
  const int c  = (blk >> 2) & 31;
  const int b  = blk >> 7;
  const int row0 = b * 1024 + c * TC;
  const int PL = 4096 * 128;
  __shared__ float Bs[TC * 16], Cs[TC * 16];
  for (int i = tid; i < TC * 16; i += 256) {
    int t = i >> 4, n = i & 15;
    const float* p = Cpart + (size_t)(row0 + t) * 128 + 64 + n;
    Bs[i] = p[0] + p[PL] + p[2 * PL] + p[3 * PL];
    Cs[i] = p[16] + p[16 + PL] + p[16 + 2 * PL] + p[16 + 3 * PL];
  }
  __syncthreads();
  // ---- phase A ----
  #pragma unroll 1
  for (int half = 0; half < 2; ++half) {
    const int d = xb * 512 + half * 256 + tid;
    float a[16];
    #pragma unroll
    for (int n = 0; n < 16; ++n) a[n] = -__expf(A_log[d * 16 + n]);
    float h[16] = {};
    float sumdt = 0.f;
    for (int t = 0; t < TC; ++t) {
      const int row = row0 + t;
      float dtv = (float)dt[(size_t)row * 2048 + d];
      float uv  = (float)u[(size_t)row * 2048 + d];
      float dtu = dtv * uv;
      sumdt += dtv;
      #pragma unroll
      for (int n = 0; n < 16; ++n)
        h[n] = h[n] * __expf(dtv * a[n]) + dtu * Bs[t * 16 + n];
    }
    const size_t base = (size_t)(b * NCH + c) * 16 * 2048 + d;
    #pragma unroll
    for (int n = 0; n < 16; ++n) {
      P[base + n * 2048] = __expf(sumdt * a[n]);
      S[base + n * 2048] = h[n];
    }
  }
  __threadfence();
  gg.sync();
  // ---- phase B: combine (512*256 threads = 4*16*2048) ----
  {
    int idx = blk * 256 + tid;
    int dd = idx & 2047, nn = (idx >> 11) & 15, bb = idx >> 15;
    float H = 0.f;
    for (int cc = 0; cc < NCH - 1; ++cc) {
      size_t off = ((size_t)(bb * NCH + cc) * 16 + nn) * 2048 + dd;
      H = P[off] * H + S[off];
      P[off] = H;
    }
  }
  __threadfence();
  gg.sync();
  // ---- phase C ----
  #pragma unroll 1
  for (int half = 0; half < 2; ++half) {
    const int d = xb * 512 + half * 256 + tid;
    float a[16];
    #pragma unroll
    for (int n = 0; n < 16; ++n) a[n] = -__expf(A_log[d * 16 + n]);
    float h[16];
    if (c == 0) {
      #pragma unroll
      for (int n = 0; n < 16; ++n) h[n] = 0.f;
    } else {
      const size_t hb = (size_t)(b * NCH + (c - 1)) * 16 * 2048 + d;
      #pragma unroll
      for (int n = 0; n < 16; ++n) h[n] = P[hb + n * 2048];
    }
    const float Dd = Dv[d];
    for (int t = 0; t < TC; ++t) {
      const int row = row0 + t;
      float dtv = (float)dt[(size_t)row * 2048 + d];
      float uv  = (float)u[(size_t)row * 2048 + d];
      float zv  = (float)zs[(size_t)row * 2048 + d];
      float dtu = dtv * uv;
      float y = uv * Dd;
      #pragma unroll
      for (int n = 0; n < 16; ++n) {
        h[n] = h[n] * __expf(dtv * a[n]) + dtu * Bs[t * 16 + n];
        y = fmaf(h[n], Cs[t * 16 + n], y);
      }
      ys[(size_t)row * 2048 + d] = (_Float16)(y * zv);
    }
  }
}

// ---------------- residual + G4-reduce + LayerNorm + LeakyReLU ----------------
__global__ __launch_bounds__(256) void k_resid_ln(
    const float* __restrict__ x, const float* __restrict__ yp,
    const float* __restrict__ gamma, const float* __restrict__ beta,
    float* __restrict__ out)
{
  int row = blockIdx.x;
  int tid = threadIdx.x;
  const int PL = 4096 * 1024;
  float v[4];
  float s = 0.f, s2 = 0.f;
  #pragma unroll
  for (int i = 0; i < 4; ++i) {
    int c = tid + i * 256;
    size_t off = (size_t)row * 1024 + c;
    float h = x[off] + yp[off] + yp[off + PL];
    v[i] = h; s += h; s2 += h * h;
  }
  #pragma unroll
  for (int off = 32; off > 0; off >>= 1) {
    s  += __shfl_down(s, off, 64);
    s2 += __shfl_down(s2, off, 64);
  }
  __shared__ float rs[4], rs2[4];
  int wv = tid >> 6, ln = tid & 63;
  if (ln == 0) { rs[wv] = s; rs2[wv] = s2; }
  __syncthreads();
  if (tid == 0) {
    float a = 0.f, b2 = 0.f;
    #pragma unroll
    for (int i = 0; i < 4; ++i) { a += rs[i]; b2 += rs2[i]; }
    rs[0] = a; rs2[0] = b2;
  }
  __syncthreads();
  float mu  = rs[0] * (1.f / 1024.f);
  float var = rs2[0] * (1.f / 1024.f) - mu * mu;
  float inv = rsqrtf(var + 1e-5f);
  #pragma unroll
  for (int i = 0; i < 4; ++i) {
    int c = tid + i * 256;
    float hn = (v[i] - mu) * inv * gamma[c] + beta[c];
    out[(size_t)row * 1024 + c] = hn >= 0.f ? hn : 0.01f * hn;
  }
}

extern "C" void kernel_launch(void* const* d_in, const int* in_sizes, int n_in,
                              void* d_out, int out_size, void* d_ws, size_t ws_size,
                              hipStream_t stream)
{
  const float* x     = (const float*)d_in[0];
  const float* W_in  = (const float*)d_in[1];
  const float* convw = (const float*)d_in[2];
  const float* convb = (const float*)d_in[3];
  const float* W_x   = (const float*)d_in[4];
  const float* W_dt  = (const float*)d_in[5];
  const float* b_dt  = (const float*)d_in[6];
  const float* A_log = (const float*)d_in[7];
  const float* Dv    = (const float*)d_in[8];
  const float* W_out = (const float*)d_in[9];
  const float* gamma = (const float*)d_in[10];
  const float* beta  = (const float*)d_in[11];
  float* out = (float*)d_out;

  char* ws = (char*)d_ws;
  const size_t MB = 1ull << 20;
  _Float16* x16   = (_Float16*)(ws + 0 * MB);    // 8 MB   (dies after G1)
  _Float16* WinT  = (_Float16*)(ws + 8 * MB);    // 8 MB   (dies after G1)
  _Float16* xc16  = (_Float16*)(ws + 16 * MB);   // 16 MB  pre-conv (dies after conv)
  _Float16* zsil  = (_Float16*)(ws + 32 * MB);   // 16 MB  silu(z)
  _Float16* xcs   = (_Float16*)(ws + 48 * MB);   // 16 MB  post-conv u
  _Float16* dtb   = (_Float16*)(ws + 64 * MB);   // 16 MB  softplus(dt); ys aliases it in scan C
  _Float16* WxT   = (_Float16*)(ws + 80 * MB);   // 0.5 MB 128x2048
  _Float16* WdtT  = (_Float16*)(ws + 80 * MB + 512 * 1024);  // 0.25 MB
  _Float16* WoutT = (_Float16*)(ws + 81 * MB);   // 4 MB   1024x2048
  float*    Cpart = (float*)   (ws + 85 * MB);   // 8 MB   G2 partials (4 planes 4096x128)
  float*    Pb    = (float*)   (ws + 0 * MB);    // 16 MB  reuse x16+WinT
  float*    Sb    = (float*)   (ws + 16 * MB);   // 16 MB  reuse xc16
  _Float16* ysb   = dtb;                         // alias (safe: read-before-write per element)
  float*    yp    = (float*)   (ws + 0 * MB);    // 32 MB  G4 partials (P,S dead)

  // 1. fused prep: cast x + 4 weight transposes
  k_prep<<<10624, 256, 0, stream>>>(x, x16, W_in, WinT, W_x, WxT, W_dt, WdtT, W_out, WoutT);
  // 2. G1: xz = x @ W_in ; xc f16 + silu(z) f16
  k_gemm_bt<3><<<dim3(32, 32), 256, 0, stream>>>(x16, WinT, nullptr, xc16, zsil, 4096, 4096, 1024);
  // 3. causal conv + SiLU
  k_conv_silu<<<4096 * 2048 / 256, 256, 0, stream>>>(xc16, convw, convb, xcs);
  // 4. G2 split-K x4 -> Cpart (dt | B | C | pad planes)
  k_gemm_bt<4><<<dim3(1, 32, 4), 256, 0, stream>>>(xcs, WxT, Cpart, nullptr, nullptr, 4096, 128, 2048);
  // 5. G3 (fused split-K reduce in A-staging): dt = softplus(dtin @ W_dt + b_dt)
  k_g3<<<dim3(16, 32), 256, 0, stream>>>(Cpart, WdtT, b_dt, dtb);
  // 6. cooperative chunked scan (A/B/C) -> ysb
  {
    const _Float16* a0 = dtb; const _Float16* a1 = xcs; const _Float16* a2 = zsil;
    const float* a3 = Cpart; const float* a4 = A_log; const float* a5 = Dv;
    float* a6 = Pb; float* a7 = Sb; _Float16* a8 = ysb;
    void* args[] = {&a0, &a1, &a2, &a3, &a4, &a5, &a6, &a7, &a8};
    hipLaunchCooperativeKernel((void*)k_scan_all, dim3(512), dim3(256), args, 0, stream);
  }
  // 7. G4 split-K x2 -> yp partials
  k_gemm_bt<4><<<dim3(8, 32, 2), 256, 0, stream>>>(ysb, WoutT, yp, nullptr, nullptr, 4096, 1024, 2048);
  // 8. residual + G4-reduce + LN + LeakyReLU
  k_resid_ln<<<4096, 256, 0, stream>>>(x, yp, gamma, beta, out);
}

// Round 6
// 375.531 us; speedup vs baseline: 1.7187x; 1.7187x over previous
//
#include <hip/hip_runtime.h>
#include <hip/hip_fp16.h>
#include <cstdint>
#include <cstddef>

typedef _Float16 f16x8 __attribute__((ext_vector_type(8)));
typedef _Float16 f16x4 __attribute__((ext_vector_type(4)));
typedef float    f32x4 __attribute__((ext_vector_type(4)));

#define TC  32   // scan chunk length
#define NCH 32   // chunks per sequence (1024 / TC)

__device__ __forceinline__ float sigmoidf_(float x) { return 1.f / (1.f + __expf(-x)); }

// async global -> LDS, 16 bytes per lane (wave-uniform base + lane*16)
__device__ __forceinline__ void gload_lds16(const _Float16* g, _Float16* l) {
  __builtin_amdgcn_global_load_lds(
      (const __attribute__((address_space(1))) void*)g,
      (__attribute__((address_space(3))) void*)l, 16, 0, 0);
}

// ---------------- fused prep: cast x + transpose W_in/W_x/W_dt/W_out ----------------
__device__ __forceinline__ void t16_body(const float* __restrict__ src,
    _Float16* __restrict__ dst, int R, int C, int Cpad, int bx, int by,
    int tid, float tile[32][33]) {
  int c0 = bx * 32, r0 = by * 32, tx = tid & 31, ty = tid >> 5;  // 32 x 8
  #pragma unroll
  for (int i = 0; i < 4; ++i) {
    int r = r0 + ty + i * 8, c = c0 + tx;
    tile[ty + i * 8][tx] = (r < R && c < C) ? src[(size_t)r * C + c] : 0.f;
  }
  __syncthreads();
  #pragma unroll
  for (int i = 0; i < 4; ++i) {
    int cc = c0 + ty + i * 8, rr = r0 + tx;
    if (cc < Cpad && rr < R) dst[(size_t)cc * R + rr] = (_Float16)tile[tx][ty + i * 8];
  }
}

__global__ __launch_bounds__(256) void k_prep(
    const float* __restrict__ x, _Float16* __restrict__ x16,
    const float* __restrict__ W_in, _Float16* __restrict__ WinT,
    const float* __restrict__ W_x, _Float16* __restrict__ WxT,
    const float* __restrict__ W_dt, _Float16* __restrict__ WdtT,
    const float* __restrict__ W_out, _Float16* __restrict__ WoutT)
{
  __shared__ float tile[32][33];
  const int blk = blockIdx.x, tid = threadIdx.x;
  if (blk < 4096) {                       // cast x: 4096x1024 via float4
    int i = blk * 256 + tid;
    float4 v = ((const float4*)x)[i];
    f16x4 o = {(_Float16)v.x, (_Float16)v.y, (_Float16)v.z, (_Float16)v.w};
    ((f16x4*)x16)[i] = o;
  } else if (blk < 8192) {                // W_in (1024x4096) -> 4096x1024
    int b = blk - 4096;
    t16_body(W_in, WinT, 1024, 4096, 4096, b & 127, b >> 7, tid, tile);
  } else if (blk < 8448) {                // W_x (2048x96) -> 128x2048 (pad)
    int b = blk - 8192;
    t16_body(W_x, WxT, 2048, 96, 128, b & 3, b >> 2, tid, tile);
  } else if (blk < 8576) {                // W_dt (64x2048) -> 2048x64
    int b = blk - 8448;
    t16_body(W_dt, WdtT, 64, 2048, 2048, b & 63, b >> 6, tid, tile);
  } else {                                // W_out (2048x1024) -> 1024x2048
    int b = blk - 8576;
    t16_body(W_out, WoutT, 2048, 1024, 1024, b & 31, b >> 5, tid, tile);
  }
}

// ---------------- MFMA GEMM, BK=64: C(MxN) = A(MxK) * BT(NxK)^T ----------------
// EPI 3: col<2048 -> C16 f16 (xc); col>=2048 -> AUX f16 = silu(v) (z)   (G1)
// EPI 4: C f32 partial, split-K over blockIdx.z (G2 z=4, G4 z=2)
template <int EPI>
__global__ __launch_bounds__(256) void k_gemm_bt(
    const _Float16* __restrict__ A,   // M x K
    const _Float16* __restrict__ BT,  // N x K
    float* __restrict__ C,
    _Float16* __restrict__ C16,
    _Float16* __restrict__ AUX,
    int M, int N, int K)
{
  // 128 rows x 64 cols f16 per tile; row = 128 B; slot s at row r stored at phys s^(r&7)
  __shared__ __align__(16) _Float16 As[128 * 64];
  __shared__ __align__(16) _Float16 Bs[128 * 64];
  const int tid  = threadIdx.x;
  const int lane = tid & 63;
  const int wave = tid >> 6;
  const int wm = (wave >> 1) * 64;
  const int wn = (wave & 1) * 64;
  const int l15 = lane & 15;
  const int q   = lane >> 4;
  const int m0 = blockIdx.y * 128;
  const int n0 = blockIdx.x * 128;

  const int kpb = K / gridDim.z;
  const int k0  = blockIdx.z * kpb;

  const int rch = lane >> 3;
  const int g   = (lane & 7) ^ (rch & 7);
  const _Float16* gA = A  + (size_t)(m0 + wave * 32 + rch) * K + k0 + g * 8;
  const _Float16* gB = BT + (size_t)(n0 + wave * 32 + rch) * K + k0 + g * 8;
  _Float16* lA = As + wave * 32 * 64 + lane * 8;
  _Float16* lB = Bs + wave * 32 * 64 + lane * 8;

  const int sx = l15 & 7;

  f32x4 acc[4][4] = {};

  for (int k = 0; k < kpb; k += 64) {
    #pragma unroll
    for (int c = 0; c < 4; ++c) {
      gload_lds16(gA + (size_t)(c * 8) * K + k, lA + c * 512);
      gload_lds16(gB + (size_t)(c * 8) * K + k, lB + c * 512);
    }
    __syncthreads();
    #pragma unroll
    for (int k32 = 0; k32 < 2; ++k32) {
      f16x8 af[4], bf[4];
      #pragma unroll
      for (int i = 0; i < 4; ++i) {
        af[i] = *(const f16x8*)&As[(wm + i * 16 + l15) * 64 + ((k32 * 4 + q) ^ sx) * 8];
        bf[i] = *(const f16x8*)&Bs[(wn + i * 16 + l15) * 64 + ((k32 * 4 + q) ^ sx) * 8];
      }
      #pragma unroll
      for (int mi = 0; mi < 4; ++mi)
        #pragma unroll
        for (int ni = 0; ni < 4; ++ni)
          acc[mi][ni] = __builtin_amdgcn_mfma_f32_16x16x32_f16(af[mi], bf[ni], acc[mi][ni], 0, 0, 0);
    }
    __syncthreads();
  }

  #pragma unroll
  for (int mi = 0; mi < 4; ++mi) {
    #pragma unroll
    for (int ni = 0; ni < 4; ++ni) {
      int col = n0 + wn + ni * 16 + l15;
      #pragma unroll
      for (int r = 0; r < 4; ++r) {
        int row = m0 + wm + mi * 16 + q * 4 + r;
        float v = acc[mi][ni][r];
        if constexpr (EPI == 3) {
          if (col < 2048) {
            C16[(size_t)row * 2048 + col] = (_Float16)v;
          } else {
            AUX[(size_t)row * 2048 + (col - 2048)] = (_Float16)(v * sigmoidf_(v));
          }
        } else {  // EPI == 4
          C[(size_t)blockIdx.z * M * N + (size_t)row * N + col] = v;
        }
      }
    }
  }
}

// ---------------- G3: dt = softplus( sum_z(Cpart cols0..63) @ W_dt + b_dt ) ----------------
__global__ __launch_bounds__(256) void k_g3(
    const float* __restrict__ Cpart,   // 4 x (4096 x 128) partials
    const _Float16* __restrict__ BT,   // WdtT: 2048 x 64
    const float* __restrict__ bias,    // b_dt
    _Float16* __restrict__ AUX)        // dtb: 4096 x 2048
{
  __shared__ __align__(16) _Float16 As2[128 * 72];
  __shared__ __align__(16) _Float16 Bs[128 * 64];
  const int tid  = threadIdx.x;
  const int lane = tid & 63;
  const int wave = tid >> 6;
  const int wm = (wave >> 1) * 64;
  const int wn = (wave & 1) * 64;
  const int l15 = lane & 15;
  const int q   = lane >> 4;
  const int m0 = blockIdx.y * 128;
  const int n0 = blockIdx.x * 128;
  const int PL = 4096 * 128;

  #pragma unroll
  for (int i = 0; i < 4; ++i) {
    int idx = i * 256 + tid;
    int r = idx >> 3, s = idx & 7;
    const float* p = Cpart + (size_t)(m0 + r) * 128 + s * 8;
    f16x8 o;
    #pragma unroll
    for (int j = 0; j < 8; ++j)
      o[j] = (_Float16)(p[j] + p[j + PL] + p[j + 2 * PL] + p[j + 3 * PL]);
    *(f16x8*)&As2[r * 72 + s * 8] = o;
  }
  const int rch = lane >> 3;
  const int g   = (lane & 7) ^ (rch & 7);
  const _Float16* gB = BT + (size_t)(n0 + wave * 32 + rch) * 64 + g * 8;
  _Float16* lB = Bs + wave * 32 * 64 + lane * 8;
  #pragma unroll
  for (int c = 0; c < 4; ++c)
    gload_lds16(gB + (size_t)(c * 8) * 64, lB + c * 512);
  __syncthreads();

  const int sx = l15 & 7;
  f32x4 acc[4][4] = {};
  #pragma unroll
  for (int k32 = 0; k32 < 2; ++k32) {
    f16x8 af[4], bf[4];
    #pragma unroll
    for (int i = 0; i < 4; ++i) {
      af[i] = *(const f16x8*)&As2[(wm + i * 16 + l15) * 72 + (k32 * 4 + q) * 8];
      bf[i] = *(const f16x8*)&Bs[(wn + i * 16 + l15) * 64 + ((k32 * 4 + q) ^ sx) * 8];
    }
    #pragma unroll
    for (int mi = 0; mi < 4; ++mi)
      #pragma unroll
      for (int ni = 0; ni < 4; ++ni)
        acc[mi][ni] = __builtin_amdgcn_mfma_f32_16x16x32_f16(af[mi], bf[ni], acc[mi][ni], 0, 0, 0);
  }

  #pragma unroll
  for (int mi = 0; mi < 4; ++mi) {
    #pragma unroll
    for (int ni = 0; ni < 4; ++ni) {
      int col = n0 + wn + ni * 16 + l15;
      #pragma unroll
      for (int r = 0; r < 4; ++r) {
        int row = m0 + wm + mi * 16 + q * 4 + r;
        float t = acc[mi][ni][r] + bias[col];
        float sp = (t > 20.f) ? t : log1pf(__expf(t));
        AUX[(size_t)row * 2048 + col] = (_Float16)sp;
      }
    }
  }
}

// ---------------- causal depthwise conv (k=4) + SiLU, f16 in/out ----------------
__global__ __launch_bounds__(256) void k_conv_silu(
    const _Float16* __restrict__ xc, const float* __restrict__ cw,
    const float* __restrict__ cb, _Float16* __restrict__ out)
{
  int idx = blockIdx.x * 256 + threadIdx.x;  // over 4096*2048
  int d = idx & 2047;
  int row = idx >> 11;
  int t = row & 1023;
  const _Float16* p = xc + (size_t)row * 2048 + d;
  float acc = cb[d] + cw[d * 4 + 3] * (float)p[0];
  if (t >= 1) acc += cw[d * 4 + 2] * (float)p[-2048];
  if (t >= 2) acc += cw[d * 4 + 1] * (float)p[-4096];
  if (t >= 3) acc += cw[d * 4 + 0] * (float)p[-6144];
  out[idx] = (_Float16)(acc * sigmoidf_(acc));
}

// ---------------- scan phase A: per-chunk local scan -> P, S ----------------
// grid (8, NCH, 4); B columns summed from G2 split-K partials in staging
__global__ __launch_bounds__(256) void k_scan_part(
    const _Float16* __restrict__ dt, const _Float16* __restrict__ u,
    const float* __restrict__ Cpart, const float* __restrict__ A_log,
    float* __restrict__ P, float* __restrict__ S)
{
  const int tid = threadIdx.x;
  const int d = blockIdx.x * 256 + tid;
  const int c = blockIdx.y;
  const int b = blockIdx.z;
  const int row0 = b * 1024 + c * TC;
  const int PL = 4096 * 128;
  __shared__ float Bs[TC * 16];
  for (int i = tid; i < TC * 16; i += 256) {
    int t = i >> 4, n = i & 15;
    const float* p = Cpart + (size_t)(row0 + t) * 128 + 64 + n;
    Bs[i] = p[0] + p[PL] + p[2 * PL] + p[3 * PL];
  }
  float a[16];
  #pragma unroll
  for (int n = 0; n < 16; ++n) a[n] = -__expf(A_log[d * 16 + n]);
  float h[16] = {};
  float sumdt = 0.f;
  __syncthreads();
  for (int t = 0; t < TC; ++t) {
    const int row = row0 + t;
    float dtv = (float)dt[(size_t)row * 2048 + d];
    float uv  = (float)u[(size_t)row * 2048 + d];
    float dtu = dtv * uv;
    sumdt += dtv;
    #pragma unroll
    for (int n = 0; n < 16; ++n)
      h[n] = h[n] * __expf(dtv * a[n]) + dtu * Bs[t * 16 + n];
  }
  const size_t base = (size_t)(b * NCH + c) * 16 * 2048 + d;
  #pragma unroll
  for (int n = 0; n < 16; ++n) {
    P[base + n * 2048] = __expf(sumdt * a[n]);
    S[base + n * 2048] = h[n];
  }
}

// ---------------- scan phase B: combine chunk states (in-place into P) ----------------
__global__ __launch_bounds__(256) void k_scan_comb(
    float* __restrict__ P, const float* __restrict__ S)
{
  int idx = blockIdx.x * 256 + threadIdx.x;
  int d = idx & 2047;
  int n = (idx >> 11) & 15;
  int b = idx >> 15;
  float H = 0.f;
  for (int c = 0; c < NCH - 1; ++c) {
    size_t off = ((size_t)(b * NCH + c) * 16 + n) * 2048 + d;
    H = P[off] * H + S[off];
    P[off] = H;
  }
}

// ---------------- scan phase C: seeded local scan -> y, gate ----------------
// NOTE: ys aliases dt (element-wise read-before-write) -> no __restrict__ on those
__global__ __launch_bounds__(256) void k_scan_y(
    const _Float16* dt, const _Float16* __restrict__ u,
    const _Float16* __restrict__ zs, const float* __restrict__ Cpart,
    const float* __restrict__ A_log, const float* __restrict__ Hbuf,
    const float* __restrict__ Dv, _Float16* ys)
{
  const int tid = threadIdx.x;
  const int d = blockIdx.x * 256 + tid;
  const int c = blockIdx.y;
  const int b = blockIdx.z;
  const int row0 = b * 1024 + c * TC;
  const int PL = 4096 * 128;
  __shared__ float Bs[TC * 16], Cs[TC * 16];
  for (int i = tid; i < TC * 16; i += 256) {
    int t = i >> 4, n = i & 15;
    const float* p = Cpart + (size_t)(row0 + t) * 128 + 64 + n;
    Bs[i] = p[0] + p[PL] + p[2 * PL] + p[3 * PL];
    Cs[i] = p[16] + p[16 + PL] + p[16 + 2 * PL] + p[16 + 3 * PL];
  }
  float a[16];
  #pragma unroll
  for (int n = 0; n < 16; ++n) a[n] = -__expf(A_log[d * 16 + n]);
  float h[16];
  if (c == 0) {
    #pragma unroll
    for (int n = 0; n < 16; ++n) h[n] = 0.f;
  } else {
    const size_t hb = (size_t)(b * NCH + (c - 1)) * 16 * 2048 + d;
    #pragma unroll
    for (int n = 0; n < 16; ++n) h[n] = Hbuf[hb + n * 2048];
  }
  const float Dd = Dv[d];
  __syncthreads();
  for (int t = 0; t < TC; ++t) {
    const int row = row0 + t;
    float dtv = (float)dt[(size_t)row * 2048 + d];
    float uv  = (float)u[(size_t)row * 2048 + d];
    float zv  = (float)zs[(size_t)row * 2048 + d];
    float dtu = dtv * uv;
    float y = uv * Dd;
    #pragma unroll
    for (int n = 0; n < 16; ++n) {
      h[n] = h[n] * __expf(dtv * a[n]) + dtu * Bs[t * 16 + n];
      y = fmaf(h[n], Cs[t * 16 + n], y);
    }
    ys[(size_t)row * 2048 + d] = (_Float16)(y * zv);
  }
}

// ---------------- residual + G4-reduce + LayerNorm + LeakyReLU ----------------
__global__ __launch_bounds__(256) void k_resid_ln(
    const float* __restrict__ x, const float* __restrict__ yp,
    const float* __restrict__ gamma, const float* __restrict__ beta,
    float* __restrict__ out)
{
  int row = blockIdx.x;
  int tid = threadIdx.x;
  const int PL = 4096 * 1024;
  float v[4];
  float s = 0.f, s2 = 0.f;
  #pragma unroll
  for (int i = 0; i < 4; ++i) {
    int c = tid + i * 256;
    size_t off = (size_t)row * 1024 + c;
    float h = x[off] + yp[off] + yp[off + PL];
    v[i] = h; s += h; s2 += h * h;
  }
  #pragma unroll
  for (int off = 32; off > 0; off >>= 1) {
    s  += __shfl_down(s, off, 64);
    s2 += __shfl_down(s2, off, 64);
  }
  __shared__ float rs[4], rs2[4];
  int wv = tid >> 6, ln = tid & 63;
  if (ln == 0) { rs[wv] = s; rs2[wv] = s2; }
  __syncthreads();
  if (tid == 0) {
    float a = 0.f, b2 = 0.f;
    #pragma unroll
    for (int i = 0; i < 4; ++i) { a += rs[i]; b2 += rs2[i]; }
    rs[0] = a; rs2[0] = b2;
  }
  __syncthreads();
  float mu  = rs[0] * (1.f / 1024.f);
  float var = rs2[0] * (1.f / 1024.f) - mu * mu;
  float inv = rsqrtf(var + 1e-5f);
  #pragma unroll
  for (int i = 0; i < 4; ++i) {
    int c = tid + i * 256;
    float hn = (v[i] - mu) * inv * gamma[c] + beta[c];
    out[(size_t)row * 1024 + c] = hn >= 0.f ? hn : 0.01f * hn;
  }
}

extern "C" void kernel_launch(void* const* d_in, const int* in_sizes, int n_in,
                              void* d_out, int out_size, void* d_ws, size_t ws_size,
                              hipStream_t stream)
{
  const float* x     = (const float*)d_in[0];
  const float* W_in  = (const float*)d_in[1];
  const float* convw = (const float*)d_in[2];
  const float* convb = (const float*)d_in[3];
  const float* W_x   = (const float*)d_in[4];
  const float* W_dt  = (const float*)d_in[5];
  const float* b_dt  = (const float*)d_in[6];
  const float* A_log = (const float*)d_in[7];
  const float* Dv    = (const float*)d_in[8];
  const float* W_out = (const float*)d_in[9];
  const float* gamma = (const float*)d_in[10];
  const float* beta  = (const float*)d_in[11];
  float* out = (float*)d_out;

  char* ws = (char*)d_ws;
  const size_t MB = 1ull << 20;
  _Float16* x16   = (_Float16*)(ws + 0 * MB);    // 8 MB   (dies after G1)
  _Float16* WinT  = (_Float16*)(ws + 8 * MB);    // 8 MB   (dies after G1)
  _Float16* xc16  = (_Float16*)(ws + 16 * MB);   // 16 MB  pre-conv (dies after conv)
  _Float16* zsil  = (_Float16*)(ws + 32 * MB);   // 16 MB  silu(z)
  _Float16* xcs   = (_Float16*)(ws + 48 * MB);   // 16 MB  post-conv u
  _Float16* dtb   = (_Float16*)(ws + 64 * MB);   // 16 MB  softplus(dt); ys aliases it
  _Float16* WxT   = (_Float16*)(ws + 80 * MB);   // 0.5 MB 128x2048
  _Float16* WdtT  = (_Float16*)(ws + 80 * MB + 512 * 1024);  // 0.25 MB
  _Float16* WoutT = (_Float16*)(ws + 81 * MB);   // 4 MB   1024x2048
  float*    Cpart = (float*)   (ws + 85 * MB);   // 8 MB   G2 partials (4 x 4096x128)
  float*    Pb    = (float*)   (ws + 0 * MB);    // 16 MB  reuse x16+WinT (scan)
  float*    Sb    = (float*)   (ws + 16 * MB);   // 16 MB  reuse xc16 (scan)
  _Float16* ysb   = dtb;                         // alias (element-wise read-before-write)
  float*    yp    = (float*)   (ws + 0 * MB);    // 32 MB  G4 partials (P,S dead after scan_y)

  // 1. fused prep: cast x + 4 weight transposes
  k_prep<<<10624, 256, 0, stream>>>(x, x16, W_in, WinT, W_x, WxT, W_dt, WdtT, W_out, WoutT);
  // 2. G1: xz = x @ W_in ; xc f16 + silu(z) f16
  k_gemm_bt<3><<<dim3(32, 32), 256, 0, stream>>>(x16, WinT, nullptr, xc16, zsil, 4096, 4096, 1024);
  // 3. causal conv + SiLU
  k_conv_silu<<<4096 * 2048 / 256, 256, 0, stream>>>(xc16, convw, convb, xcs);
  // 4. G2 split-K x4 -> Cpart
  k_gemm_bt<4><<<dim3(1, 32, 4), 256, 0, stream>>>(xcs, WxT, Cpart, nullptr, nullptr, 4096, 128, 2048);
  // 5. G3 (fused split-K reduce in A-staging): dt = softplus(dtin @ W_dt + b_dt)
  k_g3<<<dim3(16, 32), 256, 0, stream>>>(Cpart, WdtT, b_dt, dtb);
  // 6-8. chunked selective scan (3 dispatches; inter-kernel barrier = cheap XCD-coherence point)
  k_scan_part<<<dim3(8, NCH, 4), 256, 0, stream>>>(dtb, xcs, Cpart, A_log, Pb, Sb);
  k_scan_comb<<<4 * 16 * 2048 / 256, 256, 0, stream>>>(Pb, Sb);
  k_scan_y<<<dim3(8, NCH, 4), 256, 0, stream>>>(dtb, xcs, zsil, Cpart, A_log, Pb, Dv, ysb);
  // 9. G4 split-K x2 -> yp partials
  k_gemm_bt<4><<<dim3(8, 32, 2), 256, 0, stream>>>(ysb, WoutT, yp, nullptr, nullptr, 4096, 1024, 2048);
  // 10. residual + G4-reduce + LN + LeakyReLU
  k_resid_ln<<<4096, 256, 0, stream>>>(x, yp, gamma, beta, out);
}

// Round 7
// 372.525 us; speedup vs baseline: 1.7326x; 1.0081x over previous
//
#include <hip/hip_runtime.h>
#include <hip/hip_fp16.h>
#include <cstdint>
#include <cstddef>

typedef _Float16 f16x8 __attribute__((ext_vector_type(8)));
typedef _Float16 f16x4 __attribute__((ext_vector_type(4)));
typedef float    f32x4 __attribute__((ext_vector_type(4)));

#define TC  64   // scan chunk length
#define NCH 16   // chunks per sequence (1024 / TC)

__device__ __forceinline__ float sigmoidf_(float x) { return 1.f / (1.f + __expf(-x)); }

// async global -> LDS, 16 bytes per lane (wave-uniform base + lane*16)
__device__ __forceinline__ void gload_lds16(const _Float16* g, _Float16* l) {
  __builtin_amdgcn_global_load_lds(
      (const __attribute__((address_space(1))) void*)g,
      (__attribute__((address_space(3))) void*)l, 16, 0, 0);
}

// ---------------- fused prep: cast x + transposes + conv-weight planes ----------------
__device__ __forceinline__ void t16_body(const float* __restrict__ src,
    _Float16* __restrict__ dst, int R, int C, int Cpad, int bx, int by,
    int tid, float tile[32][33]) {
  int c0 = bx * 32, r0 = by * 32, tx = tid & 31, ty = tid >> 5;  // 32 x 8
  #pragma unroll
  for (int i = 0; i < 4; ++i) {
    int r = r0 + ty + i * 8, c = c0 + tx;
    tile[ty + i * 8][tx] = (r < R && c < C) ? src[(size_t)r * C + c] : 0.f;
  }
  __syncthreads();
  #pragma unroll
  for (int i = 0; i < 4; ++i) {
    int cc = c0 + ty + i * 8, rr = r0 + tx;
    if (cc < Cpad && rr < R) dst[(size_t)cc * R + rr] = (_Float16)tile[tx][ty + i * 8];
  }
}

__global__ __launch_bounds__(256) void k_prep(
    const float* __restrict__ x, _Float16* __restrict__ x16,
    const float* __restrict__ W_in, _Float16* __restrict__ WinT,
    const float* __restrict__ W_x, _Float16* __restrict__ WxT,
    const float* __restrict__ W_dt, _Float16* __restrict__ WdtT,
    const float* __restrict__ W_out, _Float16* __restrict__ WoutT,
    const float* __restrict__ convw, _Float16* __restrict__ cwT)
{
  __shared__ float tile[32][33];
  const int blk = blockIdx.x, tid = threadIdx.x;
  if (blk < 4096) {                       // cast x: 4096x1024 via float4
    int i = blk * 256 + tid;
    float4 v = ((const float4*)x)[i];
    f16x4 o = {(_Float16)v.x, (_Float16)v.y, (_Float16)v.z, (_Float16)v.w};
    ((f16x4*)x16)[i] = o;
  } else if (blk < 8192) {                // W_in (1024x4096) -> 4096x1024
    int b = blk - 4096;
    t16_body(W_in, WinT, 1024, 4096, 4096, b & 127, b >> 7, tid, tile);
  } else if (blk < 8448) {                // W_x (2048x96) -> 128x2048 (pad)
    int b = blk - 8192;
    t16_body(W_x, WxT, 2048, 96, 128, b & 3, b >> 2, tid, tile);
  } else if (blk < 8576) {                // W_dt (64x2048) -> 2048x64
    int b = blk - 8448;
    t16_body(W_dt, WdtT, 64, 2048, 2048, b & 63, b >> 6, tid, tile);
  } else if (blk < 10624) {               // W_out (2048x1024) -> 1024x2048
    int b = blk - 8576;
    t16_body(W_out, WoutT, 2048, 1024, 1024, b & 31, b >> 5, tid, tile);
  } else {                                // cwT[tap][d] = convw[d][tap], f16
    #pragma unroll
    for (int j = 0; j < 32; ++j) {
      int idx = j * 256 + tid;            // 4*2048
      int tap = idx >> 11, d = idx & 2047;
      cwT[idx] = (_Float16)convw[d * 4 + tap];
    }
  }
}

// ---------------- MFMA GEMM, BK=64: C(MxN) = A(MxK) * BT(NxK)^T ----------------
// EPI 2: AUX f16 = softplus(acc + bias[col])      (G3 -> dt)
// EPI 3: col<2048 -> C16 f16 (xc); col>=2048 -> AUX f16 = silu(v) (z)   (G1)
// EPI 4: C f32 partial, split-K over blockIdx.z (G2 z=4, G4 z=4)
template <int EPI>
__global__ __launch_bounds__(256) void k_gemm_bt(
    const _Float16* __restrict__ A,   // M x K
    const _Float16* __restrict__ BT,  // N x K
    float* __restrict__ C,
    _Float16* __restrict__ C16,
    _Float16* __restrict__ AUX,
    const float* __restrict__ bias,
    int M, int N, int K)
{
  // 128 rows x 64 cols f16 per tile; row = 128 B; slot s at row r stored at phys s^(r&7)
  __shared__ __align__(16) _Float16 As[128 * 64];
  __shared__ __align__(16) _Float16 Bs[128 * 64];
  const int tid  = threadIdx.x;
  const int lane = tid & 63;
  const int wave = tid >> 6;
  const int wm = (wave >> 1) * 64;
  const int wn = (wave & 1) * 64;
  const int l15 = lane & 15;
  const int q   = lane >> 4;
  const int m0 = blockIdx.y * 128;
  const int n0 = blockIdx.x * 128;

  const int kpb = K / gridDim.z;
  const int k0  = blockIdx.z * kpb;

  const int rch = lane >> 3;
  const int g   = (lane & 7) ^ (rch & 7);
  const _Float16* gA = A  + (size_t)(m0 + wave * 32 + rch) * K + k0 + g * 8;
  const _Float16* gB = BT + (size_t)(n0 + wave * 32 + rch) * K + k0 + g * 8;
  _Float16* lA = As + wave * 32 * 64 + lane * 8;
  _Float16* lB = Bs + wave * 32 * 64 + lane * 8;

  const int sx = l15 & 7;

  f32x4 acc[4][4] = {};

  for (int k = 0; k < kpb; k += 64) {
    #pragma unroll
    for (int c = 0; c < 4; ++c) {
      gload_lds16(gA + (size_t)(c * 8) * K + k, lA + c * 512);
      gload_lds16(gB + (size_t)(c * 8) * K + k, lB + c * 512);
    }
    __syncthreads();
    #pragma unroll
    for (int k32 = 0; k32 < 2; ++k32) {
      f16x8 af[4], bf[4];
      #pragma unroll
      for (int i = 0; i < 4; ++i) {
        af[i] = *(const f16x8*)&As[(wm + i * 16 + l15) * 64 + ((k32 * 4 + q) ^ sx) * 8];
        bf[i] = *(const f16x8*)&Bs[(wn + i * 16 + l15) * 64 + ((k32 * 4 + q) ^ sx) * 8];
      }
      #pragma unroll
      for (int mi = 0; mi < 4; ++mi)
        #pragma unroll
        for (int ni = 0; ni < 4; ++ni)
          acc[mi][ni] = __builtin_amdgcn_mfma_f32_16x16x32_f16(af[mi], bf[ni], acc[mi][ni], 0, 0, 0);
    }
    __syncthreads();
  }

  #pragma unroll
  for (int mi = 0; mi < 4; ++mi) {
    #pragma unroll
    for (int ni = 0; ni < 4; ++ni) {
      int col = n0 + wn + ni * 16 + l15;
      #pragma unroll
      for (int r = 0; r < 4; ++r) {
        int row = m0 + wm + mi * 16 + q * 4 + r;
        float v = acc[mi][ni][r];
        if constexpr (EPI == 2) {
          float t = v + bias[col];
          float sp = (t > 20.f) ? t : log1pf(__expf(t));
          AUX[(size_t)row * N + col] = (_Float16)sp;
        } else if constexpr (EPI == 3) {
          if (col < 2048) {
            C16[(size_t)row * 2048 + col] = (_Float16)v;
          } else {
            AUX[(size_t)row * 2048 + (col - 2048)] = (_Float16)(v * sigmoidf_(v));
          }
        } else {  // EPI == 4
          C[(size_t)blockIdx.z * M * N + (size_t)row * N + col] = v;
        }
      }
    }
  }
}

// ---------------- reduce G2 partials -> dtin f16 (cols<64) + xbc f32 (cols 64..95) ----------------
__global__ __launch_bounds__(256) void k_red(const float* __restrict__ Cp,
                                             _Float16* __restrict__ dtin,
                                             float* __restrict__ xbc) {
  int i = blockIdx.x * 256 + threadIdx.x;  // 4096*128
  const int PL = 4096 * 128;
  float s = Cp[i] + Cp[i + PL] + Cp[i + 2 * PL] + Cp[i + 3 * PL];
  int col = i & 127, row = i >> 7;
  if (col < 64) dtin[(size_t)row * 64 + col] = (_Float16)s;
  else if (col < 96) xbc[(size_t)row * 32 + (col - 64)] = s;
}

// ---------------- causal depthwise conv (k=4) + SiLU, f16x8 vectorized ----------------
// one row (2048 d = 256 octets) per block
__global__ __launch_bounds__(256) void k_conv_silu(
    const _Float16* __restrict__ xc, const _Float16* __restrict__ cwT,
    const float* __restrict__ cb, _Float16* __restrict__ out)
{
  const int row = blockIdx.x;          // 0..4095
  const int t = row & 1023;
  const int d8 = threadIdx.x;          // octet index
  const size_t base = (size_t)row * 2048 + d8 * 8;
  f16x8 p0 = *(const f16x8*)&xc[base];
  f16x8 w3 = *(const f16x8*)&cwT[3 * 2048 + d8 * 8];
  float4 cb0 = ((const float4*)cb)[d8 * 2];
  float4 cb1 = ((const float4*)cb)[d8 * 2 + 1];
  float accv[8] = {cb0.x, cb0.y, cb0.z, cb0.w, cb1.x, cb1.y, cb1.z, cb1.w};
  #pragma unroll
  for (int j = 0; j < 8; ++j) accv[j] += (float)w3[j] * (float)p0[j];
  if (t >= 1) {
    f16x8 p = *(const f16x8*)&xc[base - 2048];
    f16x8 w = *(const f16x8*)&cwT[2 * 2048 + d8 * 8];
    #pragma unroll
    for (int j = 0; j < 8; ++j) accv[j] += (float)w[j] * (float)p[j];
  }
  if (t >= 2) {
    f16x8 p = *(const f16x8*)&xc[base - 4096];
    f16x8 w = *(const f16x8*)&cwT[1 * 2048 + d8 * 8];
    #pragma unroll
    for (int j = 0; j < 8; ++j) accv[j] += (float)w[j] * (float)p[j];
  }
  if (t >= 3) {
    f16x8 p = *(const f16x8*)&xc[base - 6144];
    f16x8 w = *(const f16x8*)&cwT[0 * 2048 + d8 * 8];
    #pragma unroll
    for (int j = 0; j < 8; ++j) accv[j] += (float)w[j] * (float)p[j];
  }
  f16x8 o;
  #pragma unroll
  for (int j = 0; j < 8; ++j) o[j] = (_Float16)(accv[j] * sigmoidf_(accv[j]));
  *(f16x8*)&out[base] = o;
}

// ---------------- scan phase A: per-chunk local scan -> P, S ----------------
// grid (8, NCH, 4); B columns from compact xbc
__global__ __launch_bounds__(256) void k_scan_part(
    const _Float16* __restrict__ dt, const _Float16* __restrict__ u,
    const float* __restrict__ xbc, const float* __restrict__ A_log,
    float* __restrict__ P, float* __restrict__ S)
{
  const int tid = threadIdx.x;
  const int d = blockIdx.x * 256 + tid;
  const int c = blockIdx.y;
  const int b = blockIdx.z;
  const int row0 = b * 1024 + c * TC;
  __shared__ float Bs[TC * 16];
  for (int i = tid; i < TC * 16; i += 256) {
    int t = i >> 4, n = i & 15;
    Bs[i] = xbc[(size_t)(row0 + t) * 32 + n];
  }
  float a[16];
  #pragma unroll
  for (int n = 0; n < 16; ++n) a[n] = -__expf(A_log[d * 16 + n]);
  float h[16] = {};
  float sumdt = 0.f;
  __syncthreads();
  for (int t = 0; t < TC; ++t) {
    const int row = row0 + t;
    float dtv = (float)dt[(size_t)row * 2048 + d];
    float uv  = (float)u[(size_t)row * 2048 + d];
    float dtu = dtv * uv;
    sumdt += dtv;
    #pragma unroll
    for (int n = 0; n < 16; ++n)
      h[n] = h[n] * __expf(dtv * a[n]) + dtu * Bs[t * 16 + n];
  }
  const size_t base = (size_t)(b * NCH + c) * 16 * 2048 + d;
  #pragma unroll
  for (int n = 0; n < 16; ++n) {
    P[base + n * 2048] = __expf(sumdt * a[n]);
    S[base + n * 2048] = h[n];
  }
}

// ---------------- scan phase B: combine chunk states (in-place into P) ----------------
__global__ __launch_bounds__(256) void k_scan_comb(
    float* __restrict__ P, const float* __restrict__ S)
{
  int idx = blockIdx.x * 256 + threadIdx.x;   // 4*16*2048
  int d = idx & 2047;
  int n = (idx >> 11) & 15;
  int b = idx >> 15;
  float H = 0.f;
  for (int c = 0; c < NCH - 1; ++c) {
    size_t off = ((size_t)(b * NCH + c) * 16 + n) * 2048 + d;
    H = P[off] * H + S[off];
    P[off] = H;
  }
}

// ---------------- scan phase C: seeded local scan -> y, gate ----------------
// NOTE: ys aliases dt (element-wise read-before-write) -> no __restrict__ on those
__global__ __launch_bounds__(256) void k_scan_y(
    const _Float16* dt, const _Float16* __restrict__ u,
    const _Float16* __restrict__ zs, const float* __restrict__ xbc,
    const float* __restrict__ A_log, const float* __restrict__ Hbuf,
    const float* __restrict__ Dv, _Float16* ys)
{
  const int tid = threadIdx.x;
  const int d = blockIdx.x * 256 + tid;
  const int c = blockIdx.y;
  const int b = blockIdx.z;
  const int row0 = b * 1024 + c * TC;
  __shared__ float Bs[TC * 16], Cs[TC * 16];
  for (int i = tid; i < TC * 16; i += 256) {
    int t = i >> 4, n = i & 15;
    Bs[i] = xbc[(size_t)(row0 + t) * 32 + n];
    Cs[i] = xbc[(size_t)(row0 + t) * 32 + 16 + n];
  }
  float a[16];
  #pragma unroll
  for (int n = 0; n < 16; ++n) a[n] = -__expf(A_log[d * 16 + n]);
  float h[16];
  if (c == 0) {
    #pragma unroll
    for (int n = 0; n < 16; ++n) h[n] = 0.f;
  } else {
    const size_t hb = (size_t)(b * NCH + (c - 1)) * 16 * 2048 + d;
    #pragma unroll
    for (int n = 0; n < 16; ++n) h[n] = Hbuf[hb + n * 2048];
  }
  const float Dd = Dv[d];
  __syncthreads();
  for (int t = 0; t < TC; ++t) {
    const int row = row0 + t;
    float dtv = (float)dt[(size_t)row * 2048 + d];
    float uv  = (float)u[(size_t)row * 2048 + d];
    float zv  = (float)zs[(size_t)row * 2048 + d];
    float dtu = dtv * uv;
    float y = uv * Dd;
    #pragma unroll
    for (int n = 0; n < 16; ++n) {
      h[n] = h[n] * __expf(dtv * a[n]) + dtu * Bs[t * 16 + n];
      y = fmaf(h[n], Cs[t * 16 + n], y);
    }
    ys[(size_t)row * 2048 + d] = (_Float16)(y * zv);
  }
}

// ---------------- residual + G4-reduce(x4) + LayerNorm + LeakyReLU, float4 ----------------
__global__ __launch_bounds__(256) void k_resid_ln(
    const float* __restrict__ x, const float* __restrict__ yp,
    const float* __restrict__ gamma, const float* __restrict__ beta,
    float* __restrict__ out)
{
  int row = blockIdx.x;
  int tid = threadIdx.x;
  const int PL4 = 4096 * 256;   // plane stride in float4
  const int o4 = row * 256 + tid;
  float4 xv = ((const float4*)x)[o4];
  float4 p0 = ((const float4*)yp)[o4];
  float4 p1 = ((const float4*)yp)[o4 + PL4];
  float4 p2 = ((const float4*)yp)[o4 + 2 * PL4];
  float4 p3 = ((const float4*)yp)[o4 + 3 * PL4];
  float v[4] = {xv.x + p0.x + p1.x + p2.x + p3.x,
                xv.y + p0.y + p1.y + p2.y + p3.y,
                xv.z + p0.z + p1.z + p2.z + p3.z,
                xv.w + p0.w + p1.w + p2.w + p3.w};
  float s = v[0] + v[1] + v[2] + v[3];
  float s2 = v[0]*v[0] + v[1]*v[1] + v[2]*v[2] + v[3]*v[3];
  #pragma unroll
  for (int off = 32; off > 0; off >>= 1) {
    s  += __shfl_down(s, off, 64);
    s2 += __shfl_down(s2, off, 64);
  }
  __shared__ float rs[4], rs2[4];
  int wv = tid >> 6, ln = tid & 63;
  if (ln == 0) { rs[wv] = s; rs2[wv] = s2; }
  __syncthreads();
  if (tid == 0) {
    float a = 0.f, b2 = 0.f;
    #pragma unroll
    for (int i = 0; i < 4; ++i) { a += rs[i]; b2 += rs2[i]; }
    rs[0] = a; rs2[0] = b2;
  }
  __syncthreads();
  float mu  = rs[0] * (1.f / 1024.f);
  float var = rs2[0] * (1.f / 1024.f) - mu * mu;
  float inv = rsqrtf(var + 1e-5f);
  float4 gv = ((const float4*)gamma)[tid];
  float4 bv = ((const float4*)beta)[tid];
  float gg[4] = {gv.x, gv.y, gv.z, gv.w};
  float bb[4] = {bv.x, bv.y, bv.z, bv.w};
  float4 ov;
  float* op = (float*)&ov;
  #pragma unroll
  for (int i = 0; i < 4; ++i) {
    float hn = (v[i] - mu) * inv * gg[i] + bb[i];
    op[i] = hn >= 0.f ? hn : 0.01f * hn;
  }
  ((float4*)out)[o4] = ov;
}

extern "C" void kernel_launch(void* const* d_in, const int* in_sizes, int n_in,
                              void* d_out, int out_size, void* d_ws, size_t ws_size,
                              hipStream_t stream)
{
  const float* x     = (const float*)d_in[0];
  const float* W_in  = (const float*)d_in[1];
  const float* convw = (const float*)d_in[2];
  const float* convb = (const float*)d_in[3];
  const float* W_x   = (const float*)d_in[4];
  const float* W_dt  = (const float*)d_in[5];
  const float* b_dt  = (const float*)d_in[6];
  const float* A_log = (const float*)d_in[7];
  const float* Dv    = (const float*)d_in[8];
  const float* W_out = (const float*)d_in[9];
  const float* gamma = (const float*)d_in[10];
  const float* beta  = (const float*)d_in[11];
  float* out = (float*)d_out;

  char* ws = (char*)d_ws;
  const size_t MB = 1ull << 20;
  _Float16* x16   = (_Float16*)(ws + 0 * MB);    // 8 MB   (dies after G1)
  _Float16* WinT  = (_Float16*)(ws + 8 * MB);    // 8 MB   (dies after G1)
  _Float16* xc16  = (_Float16*)(ws + 16 * MB);   // 16 MB  pre-conv (dies after conv)
  _Float16* zsil  = (_Float16*)(ws + 32 * MB);   // 16 MB  silu(z)
  _Float16* xcs   = (_Float16*)(ws + 48 * MB);   // 16 MB  post-conv u
  _Float16* dtb   = (_Float16*)(ws + 64 * MB);   // 16 MB  softplus(dt); ys aliases it
  _Float16* WxT   = (_Float16*)(ws + 80 * MB);   // 0.5 MB 128x2048
  _Float16* WdtT  = (_Float16*)(ws + 80 * MB + 512 * 1024);  // 0.25 MB
  _Float16* WoutT = (_Float16*)(ws + 81 * MB);   // 4 MB   1024x2048
  float*    Cpart = (float*)   (ws + 85 * MB);   // 8 MB   G2 partials (4 x 4096x128)
  float*    xbc   = (float*)   (ws + 93 * MB);   // 0.5 MB 4096x32 (B|C sums)
  _Float16* dtin  = (_Float16*)(ws + 93 * MB + 512 * 1024);  // 0.5 MB 4096x64
  _Float16* cwT   = (_Float16*)(ws + 94 * MB);   // 16 KB  4x2048 conv weights
  float*    Pb    = (float*)   (ws + 0 * MB);    // 8 MB   (x16 dead)
  float*    Sb    = (float*)   (ws + 8 * MB);    // 8 MB   (WinT dead)
  _Float16* ysb   = dtb;                         // alias (element-wise read-before-write)
  float*    yp    = (float*)   (ws + 0 * MB);    // 64 MB  G4 partials x4 (P,S,xc16,zsil,xcs dead)

  // 1. fused prep
  k_prep<<<10625, 256, 0, stream>>>(x, x16, W_in, WinT, W_x, WxT, W_dt, WdtT,
                                    W_out, WoutT, convw, cwT);
  // 2. G1: xz = x @ W_in ; xc f16 + silu(z) f16
  k_gemm_bt<3><<<dim3(32, 32), 256, 0, stream>>>(x16, WinT, nullptr, xc16, zsil, nullptr, 4096, 4096, 1024);
  // 3. causal conv + SiLU (vectorized)
  k_conv_silu<<<4096, 256, 0, stream>>>(xc16, cwT, convb, xcs);
  // 4. G2 split-K x4 -> Cpart
  k_gemm_bt<4><<<dim3(1, 32, 4), 256, 0, stream>>>(xcs, WxT, Cpart, nullptr, nullptr, nullptr, 4096, 128, 2048);
  // 5. slim reduce -> dtin f16, xbc f32
  k_red<<<4096 * 128 / 256, 256, 0, stream>>>(Cpart, dtin, xbc);
  // 6. G3: dt = softplus(dtin @ W_dt + b_dt)  (K=64, 1 iter)
  k_gemm_bt<2><<<dim3(16, 32), 256, 0, stream>>>(dtin, WdtT, nullptr, nullptr, dtb, b_dt, 4096, 2048, 64);
  // 7-9. chunked selective scan (TC=64)
  k_scan_part<<<dim3(8, NCH, 4), 256, 0, stream>>>(dtb, xcs, xbc, A_log, Pb, Sb);
  k_scan_comb<<<4 * 16 * 2048 / 256, 256, 0, stream>>>(Pb, Sb);
  k_scan_y<<<dim3(8, NCH, 4), 256, 0, stream>>>(dtb, xcs, zsil, xbc, A_log, Pb, Dv, ysb);
  // 10. G4 split-K x4 -> yp partials
  k_gemm_bt<4><<<dim3(8, 32, 4), 256, 0, stream>>>(ysb, WoutT, yp, nullptr, nullptr, nullptr, 4096, 1024, 2048);
  // 11. residual + 4-plane reduce + LN + LeakyReLU
  k_resid_ln<<<4096, 256, 0, stream>>>(x, yp, gamma, beta, out);
}

// Round 8
// 364.700 us; speedup vs baseline: 1.7697x; 1.0215x over previous
//
#include <hip/hip_runtime.h>
#include <hip/hip_fp16.h>
#include <cstdint>
#include <cstddef>

typedef _Float16 f16x8 __attribute__((ext_vector_type(8)));
typedef _Float16 f16x4 __attribute__((ext_vector_type(4)));
typedef float    f32x4 __attribute__((ext_vector_type(4)));

#define TC  64   // scan chunk length
#define NCH 16   // chunks per sequence (1024 / TC)

__device__ __forceinline__ float sigmoidf_(float x) { return 1.f / (1.f + __expf(-x)); }

// async global -> LDS, 16 bytes per lane (wave-uniform base + lane*16)
__device__ __forceinline__ void gload_lds16(const _Float16* g, _Float16* l) {
  __builtin_amdgcn_global_load_lds(
      (const __attribute__((address_space(1))) void*)g,
      (__attribute__((address_space(3))) void*)l, 16, 0, 0);
}

// ---------------- fused prep: cast x + transposes + conv-weight planes ----------------
__device__ __forceinline__ void t16_body(const float* __restrict__ src,
    _Float16* __restrict__ dst, int R, int C, int Cpad, int bx, int by,
    int tid, float tile[32][33]) {
  int c0 = bx * 32, r0 = by * 32, tx = tid & 31, ty = tid >> 5;  // 32 x 8
  #pragma unroll
  for (int i = 0; i < 4; ++i) {
    int r = r0 + ty + i * 8, c = c0 + tx;
    tile[ty + i * 8][tx] = (r < R && c < C) ? src[(size_t)r * C + c] : 0.f;
  }
  __syncthreads();
  #pragma unroll
  for (int i = 0; i < 4; ++i) {
    int cc = c0 + ty + i * 8, rr = r0 + tx;
    if (cc < Cpad && rr < R) dst[(size_t)cc * R + rr] = (_Float16)tile[tx][ty + i * 8];
  }
}

__global__ __launch_bounds__(256) void k_prep(
    const float* __restrict__ x, _Float16* __restrict__ x16,
    const float* __restrict__ W_in, _Float16* __restrict__ WinT,
    const float* __restrict__ W_x, _Float16* __restrict__ WxT,
    const float* __restrict__ W_dt, _Float16* __restrict__ WdtT,
    const float* __restrict__ W_out, _Float16* __restrict__ WoutT,
    const float* __restrict__ convw, _Float16* __restrict__ cwT)
{
  __shared__ float tile[32][33];
  const int blk = blockIdx.x, tid = threadIdx.x;
  if (blk < 4096) {                       // cast x: 4096x1024 via float4
    int i = blk * 256 + tid;
    float4 v = ((const float4*)x)[i];
    f16x4 o = {(_Float16)v.x, (_Float16)v.y, (_Float16)v.z, (_Float16)v.w};
    ((f16x4*)x16)[i] = o;
  } else if (blk < 8192) {                // W_in (1024x4096) -> 4096x1024
    int b = blk - 4096;
    t16_body(W_in, WinT, 1024, 4096, 4096, b & 127, b >> 7, tid, tile);
  } else if (blk < 8448) {                // W_x (2048x96) -> 128x2048 (pad)
    int b = blk - 8192;
    t16_body(W_x, WxT, 2048, 96, 128, b & 3, b >> 2, tid, tile);
  } else if (blk < 8576) {                // W_dt (64x2048) -> 2048x64
    int b = blk - 8448;
    t16_body(W_dt, WdtT, 64, 2048, 2048, b & 63, b >> 6, tid, tile);
  } else if (blk < 10624) {               // W_out (2048x1024) -> 1024x2048
    int b = blk - 8576;
    t16_body(W_out, WoutT, 2048, 1024, 1024, b & 31, b >> 5, tid, tile);
  } else {                                // cwT[tap][d] = convw[d][tap], f16
    #pragma unroll
    for (int j = 0; j < 32; ++j) {
      int idx = j * 256 + tid;            // 4*2048
      int tap = idx >> 11, d = idx & 2047;
      cwT[idx] = (_Float16)convw[d * 4 + tap];
    }
  }
}

// ---------------- MFMA GEMM, BK=64: C(MxN) = A(MxK) * BT(NxK)^T ----------------
// EPI 2: AUX f16 = softplus(acc + bias[col])      (G3 -> dt)
// EPI 3: n0<2048 -> C16 f16 (xc); n0>=2048 -> AUX f16 = silu(v) (z)   (G1)
// EPI 4: C f32 partial, split-K over blockIdx.z (G2 z=4)
// EPI 5: C16 f16 partial, split-K over blockIdx.z (G4 z=2)
// EPIs 2/3/5 use an LDS-repack epilogue: 64 scalar stores -> 8 coalesced dwordx4.
template <int EPI>
__global__ __launch_bounds__(256) void k_gemm_bt(
    const _Float16* __restrict__ A,   // M x K
    const _Float16* __restrict__ BT,  // N x K
    float* __restrict__ C,
    _Float16* __restrict__ C16,
    _Float16* __restrict__ AUX,
    const float* __restrict__ bias,
    int M, int N, int K)
{
  // 128 rows x 64 cols f16 per tile; row = 128 B; slot s at row r stored at phys s^(r&7)
  __shared__ __align__(16) _Float16 As[128 * 64];
  __shared__ __align__(16) _Float16 Bs[128 * 64];
  const int tid  = threadIdx.x;
  const int lane = tid & 63;
  const int wave = tid >> 6;
  const int wm = (wave >> 1) * 64;
  const int wn = (wave & 1) * 64;
  const int l15 = lane & 15;
  const int q   = lane >> 4;
  const int m0 = blockIdx.y * 128;
  const int n0 = blockIdx.x * 128;

  const int kpb = K / gridDim.z;
  const int k0  = blockIdx.z * kpb;

  const int rch = lane >> 3;
  const int g   = (lane & 7) ^ (rch & 7);
  const _Float16* gA = A  + (size_t)(m0 + wave * 32 + rch) * K + k0 + g * 8;
  const _Float16* gB = BT + (size_t)(n0 + wave * 32 + rch) * K + k0 + g * 8;
  _Float16* lA = As + wave * 32 * 64 + lane * 8;
  _Float16* lB = Bs + wave * 32 * 64 + lane * 8;

  const int sx = l15 & 7;

  f32x4 acc[4][4] = {};

  for (int k = 0; k < kpb; k += 64) {
    #pragma unroll
    for (int c = 0; c < 4; ++c) {
      gload_lds16(gA + (size_t)(c * 8) * K + k, lA + c * 512);
      gload_lds16(gB + (size_t)(c * 8) * K + k, lB + c * 512);
    }
    __syncthreads();
    #pragma unroll
    for (int k32 = 0; k32 < 2; ++k32) {
      f16x8 af[4], bf[4];
      #pragma unroll
      for (int i = 0; i < 4; ++i) {
        af[i] = *(const f16x8*)&As[(wm + i * 16 + l15) * 64 + ((k32 * 4 + q) ^ sx) * 8];
        bf[i] = *(const f16x8*)&Bs[(wn + i * 16 + l15) * 64 + ((k32 * 4 + q) ^ sx) * 8];
      }
      #pragma unroll
      for (int mi = 0; mi < 4; ++mi)
        #pragma unroll
        for (int ni = 0; ni < 4; ++ni)
          acc[mi][ni] = __builtin_amdgcn_mfma_f32_16x16x32_f16(af[mi], bf[ni], acc[mi][ni], 0, 0, 0);
    }
    __syncthreads();
  }

  if constexpr (EPI == 4) {
    // f32 split-K partials (G2): scattered dword stores (small problem)
    #pragma unroll
    for (int mi = 0; mi < 4; ++mi) {
      #pragma unroll
      for (int ni = 0; ni < 4; ++ni) {
        int col = n0 + wn + ni * 16 + l15;
        #pragma unroll
        for (int r = 0; r < 4; ++r) {
          int row = m0 + wm + mi * 16 + q * 4 + r;
          C[(size_t)blockIdx.z * M * N + (size_t)row * N + col] = acc[mi][ni][r];
        }
      }
    }
  } else {
    // f16 LDS-repack epilogue: per wave, 16x64 patch at stride 72 (bank spread)
    _Float16* Ep = As + wave * 1280;   // 16*72 = 1152 f16, padded region per wave
    const int rr = lane >> 2, cb = lane & 3;
    #pragma unroll
    for (int mi = 0; mi < 4; ++mi) {
      #pragma unroll
      for (int ni = 0; ni < 4; ++ni) {
        int col = n0 + wn + ni * 16 + l15;
        #pragma unroll
        for (int r = 0; r < 4; ++r) {
          float v = acc[mi][ni][r];
          _Float16 hv;
          if constexpr (EPI == 2) {
            float t = v + bias[col];
            float sp = (t > 20.f) ? t : log1pf(__expf(t));
            hv = (_Float16)sp;
          } else if constexpr (EPI == 3) {
            hv = (n0 >= 2048) ? (_Float16)(v * sigmoidf_(v)) : (_Float16)v;
          } else {  // EPI == 5
            hv = (_Float16)v;
          }
          Ep[(q * 4 + r) * 72 + ni * 16 + l15] = hv;
        }
      }
      __syncthreads();
      f16x8 o0 = *(const f16x8*)&Ep[rr * 72 + cb * 16];
      f16x8 o1 = *(const f16x8*)&Ep[rr * 72 + cb * 16 + 8];
      int row = m0 + wm + mi * 16 + rr;
      int colb = wn + cb * 16;
      if constexpr (EPI == 2) {
        _Float16* dst = AUX + (size_t)row * N + n0 + colb;
        *(f16x8*)dst = o0;
        *(f16x8*)(dst + 8) = o1;
      } else if constexpr (EPI == 3) {
        if (n0 < 2048) {
          _Float16* dst = C16 + (size_t)row * 2048 + n0 + colb;
          *(f16x8*)dst = o0;
          *(f16x8*)(dst + 8) = o1;
        } else {
          _Float16* dst = AUX + (size_t)row * 2048 + (n0 - 2048) + colb;
          *(f16x8*)dst = o0;
          *(f16x8*)(dst + 8) = o1;
        }
      } else {  // EPI == 5
        _Float16* dst = C16 + (size_t)blockIdx.z * M * N + (size_t)row * N + n0 + colb;
        *(f16x8*)dst = o0;
        *(f16x8*)(dst + 8) = o1;
      }
      __syncthreads();
    }
  }
}

// ---------------- reduce G2 partials -> dtin f16 (cols<64) + xbc f32 (cols 64..95) ----------------
__global__ __launch_bounds__(256) void k_red(const float* __restrict__ Cp,
                                             _Float16* __restrict__ dtin,
                                             float* __restrict__ xbc) {
  int i = blockIdx.x * 256 + threadIdx.x;  // 4096*128
  const int PL = 4096 * 128;
  float s = Cp[i] + Cp[i + PL] + Cp[i + 2 * PL] + Cp[i + 3 * PL];
  int col = i & 127, row = i >> 7;
  if (col < 64) dtin[(size_t)row * 64 + col] = (_Float16)s;
  else if (col < 96) xbc[(size_t)row * 32 + (col - 64)] = s;
}

// ---------------- causal depthwise conv (k=4) + SiLU, f16x8 vectorized ----------------
__global__ __launch_bounds__(256) void k_conv_silu(
    const _Float16* __restrict__ xc, const _Float16* __restrict__ cwT,
    const float* __restrict__ cb, _Float16* __restrict__ out)
{
  const int row = blockIdx.x;          // 0..4095
  const int t = row & 1023;
  const int d8 = threadIdx.x;          // octet index
  const size_t base = (size_t)row * 2048 + d8 * 8;
  f16x8 p0 = *(const f16x8*)&xc[base];
  f16x8 w3 = *(const f16x8*)&cwT[3 * 2048 + d8 * 8];
  float4 cb0 = ((const float4*)cb)[d8 * 2];
  float4 cb1 = ((const float4*)cb)[d8 * 2 + 1];
  float accv[8] = {cb0.x, cb0.y, cb0.z, cb0.w, cb1.x, cb1.y, cb1.z, cb1.w};
  #pragma unroll
  for (int j = 0; j < 8; ++j) accv[j] += (float)w3[j] * (float)p0[j];
  if (t >= 1) {
    f16x8 p = *(const f16x8*)&xc[base - 2048];
    f16x8 w = *(const f16x8*)&cwT[2 * 2048 + d8 * 8];
    #pragma unroll
    for (int j = 0; j < 8; ++j) accv[j] += (float)w[j] * (float)p[j];
  }
  if (t >= 2) {
    f16x8 p = *(const f16x8*)&xc[base - 4096];
    f16x8 w = *(const f16x8*)&cwT[1 * 2048 + d8 * 8];
    #pragma unroll
    for (int j = 0; j < 8; ++j) accv[j] += (float)w[j] * (float)p[j];
  }
  if (t >= 3) {
    f16x8 p = *(const f16x8*)&xc[base - 6144];
    f16x8 w = *(const f16x8*)&cwT[0 * 2048 + d8 * 8];
    #pragma unroll
    for (int j = 0; j < 8; ++j) accv[j] += (float)w[j] * (float)p[j];
  }
  f16x8 o;
  #pragma unroll
  for (int j = 0; j < 8; ++j) o[j] = (_Float16)(accv[j] * sigmoidf_(accv[j]));
  *(f16x8*)&out[base] = o;
}

// ---------------- scan phase A: per-chunk local scan -> P, S ----------------
__global__ __launch_bounds__(256) void k_scan_part(
    const _Float16* __restrict__ dt, const _Float16* __restrict__ u,
    const float* __restrict__ xbc, const float* __restrict__ A_log,
    float* __restrict__ P, float* __restrict__ S)
{
  const int tid = threadIdx.x;
  const int d = blockIdx.x * 256 + tid;
  const int c = blockIdx.y;
  const int b = blockIdx.z;
  const int row0 = b * 1024 + c * TC;
  __shared__ float Bs[TC * 16];
  for (int i = tid; i < TC * 16; i += 256) {
    int t = i >> 4, n = i & 15;
    Bs[i] = xbc[(size_t)(row0 + t) * 32 + n];
  }
  float a[16];
  #pragma unroll
  for (int n = 0; n < 16; ++n) a[n] = -__expf(A_log[d * 16 + n]);
  float h[16] = {};
  float sumdt = 0.f;
  __syncthreads();
  for (int t = 0; t < TC; ++t) {
    const int row = row0 + t;
    float dtv = (float)dt[(size_t)row * 2048 + d];
    float uv  = (float)u[(size_t)row * 2048 + d];
    float dtu = dtv * uv;
    sumdt += dtv;
    #pragma unroll
    for (int n = 0; n < 16; ++n)
      h[n] = h[n] * __expf(dtv * a[n]) + dtu * Bs[t * 16 + n];
  }
  const size_t base = (size_t)(b * NCH + c) * 16 * 2048 + d;
  #pragma unroll
  for (int n = 0; n < 16; ++n) {
    P[base + n * 2048] = __expf(sumdt * a[n]);
    S[base + n * 2048] = h[n];
  }
}

// ---------------- scan phase B: combine chunk states (in-place into P) ----------------
__global__ __launch_bounds__(256) void k_scan_comb(
    float* __restrict__ P, const float* __restrict__ S)
{
  int idx = blockIdx.x * 256 + threadIdx.x;   // 4*16*2048
  int d = idx & 2047;
  int n = (idx >> 11) & 15;
  int b = idx >> 15;
  float H = 0.f;
  for (int c = 0; c < NCH - 1; ++c) {
    size_t off = ((size_t)(b * NCH + c) * 16 + n) * 2048 + d;
    H = P[off] * H + S[off];
    P[off] = H;
  }
}

// ---------------- scan phase C: seeded local scan -> y, gate ----------------
// NOTE: ys aliases dt (element-wise read-before-write) -> no __restrict__ on those
__global__ __launch_bounds__(256) void k_scan_y(
    const _Float16* dt, const _Float16* __restrict__ u,
    const _Float16* __restrict__ zs, const float* __restrict__ xbc,
    const float* __restrict__ A_log, const float* __restrict__ Hbuf,
    const float* __restrict__ Dv, _Float16* ys)
{
  const int tid = threadIdx.x;
  const int d = blockIdx.x * 256 + tid;
  const int c = blockIdx.y;
  const int b = blockIdx.z;
  const int row0 = b * 1024 + c * TC;
  __shared__ float Bs[TC * 16], Cs[TC * 16];
  for (int i = tid; i < TC * 16; i += 256) {
    int t = i >> 4, n = i & 15;
    Bs[i] = xbc[(size_t)(row0 + t) * 32 + n];
    Cs[i] = xbc[(size_t)(row0 + t) * 32 + 16 + n];
  }
  float a[16];
  #pragma unroll
  for (int n = 0; n < 16; ++n) a[n] = -__expf(A_log[d * 16 + n]);
  float h[16];
  if (c == 0) {
    #pragma unroll
    for (int n = 0; n < 16; ++n) h[n] = 0.f;
  } else {
    const size_t hb = (size_t)(b * NCH + (c - 1)) * 16 * 2048 + d;
    #pragma unroll
    for (int n = 0; n < 16; ++n) h[n] = Hbuf[hb + n * 2048];
  }
  const float Dd = Dv[d];
  __syncthreads();
  for (int t = 0; t < TC; ++t) {
    const int row = row0 + t;
    float dtv = (float)dt[(size_t)row * 2048 + d];
    float uv  = (float)u[(size_t)row * 2048 + d];
    float zv  = (float)zs[(size_t)row * 2048 + d];
    float dtu = dtv * uv;
    float y = uv * Dd;
    #pragma unroll
    for (int n = 0; n < 16; ++n) {
      h[n] = h[n] * __expf(dtv * a[n]) + dtu * Bs[t * 16 + n];
      y = fmaf(h[n], Cs[t * 16 + n], y);
    }
    ys[(size_t)row * 2048 + d] = (_Float16)(y * zv);
  }
}

// ---------------- residual + G4-reduce(2x f16 planes) + LayerNorm + LeakyReLU ----------------
__global__ __launch_bounds__(256) void k_resid_ln(
    const float* __restrict__ x, const _Float16* __restrict__ yp,
    const float* __restrict__ gamma, const float* __restrict__ beta,
    float* __restrict__ out)
{
  int row = blockIdx.x;
  int tid = threadIdx.x;
  const int PLH = 4096 * 1024;  // f16 plane stride (elements)
  const int o4 = row * 256 + tid;
  float4 xv = ((const float4*)x)[o4];
  f16x4 a0 = ((const f16x4*)yp)[o4];
  f16x4 a1 = ((const f16x4*)(yp + PLH))[o4];
  float v[4] = {xv.x + (float)a0[0] + (float)a1[0],
                xv.y + (float)a0[1] + (float)a1[1],
                xv.z + (float)a0[2] + (float)a1[2],
                xv.w + (float)a0[3] + (float)a1[3]};
  float s = v[0] + v[1] + v[2] + v[3];
  float s2 = v[0]*v[0] + v[1]*v[1] + v[2]*v[2] + v[3]*v[3];
  #pragma unroll
  for (int off = 32; off > 0; off >>= 1) {
    s  += __shfl_down(s, off, 64);
    s2 += __shfl_down(s2, off, 64);
  }
  __shared__ float rs[4], rs2[4];
  int wv = tid >> 6, ln = tid & 63;
  if (ln == 0) { rs[wv] = s; rs2[wv] = s2; }
  __syncthreads();
  if (tid == 0) {
    float a = 0.f, b2 = 0.f;
    #pragma unroll
    for (int i = 0; i < 4; ++i) { a += rs[i]; b2 += rs2[i]; }
    rs[0] = a; rs2[0] = b2;
  }
  __syncthreads();
  float mu  = rs[0] * (1.f / 1024.f);
  float var = rs2[0] * (1.f / 1024.f) - mu * mu;
  float inv = rsqrtf(var + 1e-5f);
  float4 gv = ((const float4*)gamma)[tid];
  float4 bv = ((const float4*)beta)[tid];
  float gg[4] = {gv.x, gv.y, gv.z, gv.w};
  float bb[4] = {bv.x, bv.y, bv.z, bv.w};
  float4 ov;
  float* op = (float*)&ov;
  #pragma unroll
  for (int i = 0; i < 4; ++i) {
    float hn = (v[i] - mu) * inv * gg[i] + bb[i];
    op[i] = hn >= 0.f ? hn : 0.01f * hn;
  }
  ((float4*)out)[o4] = ov;
}

extern "C" void kernel_launch(void* const* d_in, const int* in_sizes, int n_in,
                              void* d_out, int out_size, void* d_ws, size_t ws_size,
                              hipStream_t stream)
{
  const float* x     = (const float*)d_in[0];
  const float* W_in  = (const float*)d_in[1];
  const float* convw = (const float*)d_in[2];
  const float* convb = (const float*)d_in[3];
  const float* W_x   = (const float*)d_in[4];
  const float* W_dt  = (const float*)d_in[5];
  const float* b_dt  = (const float*)d_in[6];
  const float* A_log = (const float*)d_in[7];
  const float* Dv    = (const float*)d_in[8];
  const float* W_out = (const float*)d_in[9];
  const float* gamma = (const float*)d_in[10];
  const float* beta  = (const float*)d_in[11];
  float* out = (float*)d_out;

  char* ws = (char*)d_ws;
  const size_t MB = 1ull << 20;
  _Float16* x16   = (_Float16*)(ws + 0 * MB);    // 8 MB   (dies after G1)
  _Float16* WinT  = (_Float16*)(ws + 8 * MB);    // 8 MB   (dies after G1)
  _Float16* xc16  = (_Float16*)(ws + 16 * MB);   // 16 MB  pre-conv (dies after conv)
  _Float16* zsil  = (_Float16*)(ws + 32 * MB);   // 16 MB  silu(z)
  _Float16* xcs   = (_Float16*)(ws + 48 * MB);   // 16 MB  post-conv u
  _Float16* dtb   = (_Float16*)(ws + 64 * MB);   // 16 MB  softplus(dt); ys aliases it
  _Float16* WxT   = (_Float16*)(ws + 80 * MB);   // 0.5 MB 128x2048
  _Float16* WdtT  = (_Float16*)(ws + 80 * MB + 512 * 1024);  // 0.25 MB
  _Float16* WoutT = (_Float16*)(ws + 81 * MB);   // 4 MB   1024x2048
  float*    Cpart = (float*)   (ws + 85 * MB);   // 8 MB   G2 partials (4 x 4096x128)
  float*    xbc   = (float*)   (ws + 93 * MB);   // 0.5 MB 4096x32 (B|C sums)
  _Float16* dtin  = (_Float16*)(ws + 93 * MB + 512 * 1024);  // 0.5 MB 4096x64
  _Float16* cwT   = (_Float16*)(ws + 94 * MB);   // 16 KB  4x2048 conv weights
  float*    Pb    = (float*)   (ws + 0 * MB);    // 8 MB   (x16 dead)
  float*    Sb    = (float*)   (ws + 8 * MB);    // 8 MB   (WinT dead)
  _Float16* ysb   = dtb;                         // alias (element-wise read-before-write)
  _Float16* ypH   = (_Float16*)(ws + 0 * MB);    // 16 MB  G4 f16 partials x2 (P,S dead)

  // 1. fused prep
  k_prep<<<10625, 256, 0, stream>>>(x, x16, W_in, WinT, W_x, WxT, W_dt, WdtT,
                                    W_out, WoutT, convw, cwT);
  // 2. G1: xz = x @ W_in ; xc f16 + silu(z) f16
  k_gemm_bt<3><<<dim3(32, 32), 256, 0, stream>>>(x16, WinT, nullptr, xc16, zsil, nullptr, 4096, 4096, 1024);
  // 3. causal conv + SiLU (vectorized)
  k_conv_silu<<<4096, 256, 0, stream>>>(xc16, cwT, convb, xcs);
  // 4. G2 split-K x4 -> Cpart
  k_gemm_bt<4><<<dim3(1, 32, 4), 256, 0, stream>>>(xcs, WxT, Cpart, nullptr, nullptr, nullptr, 4096, 128, 2048);
  // 5. slim reduce -> dtin f16, xbc f32
  k_red<<<4096 * 128 / 256, 256, 0, stream>>>(Cpart, dtin, xbc);
  // 6. G3: dt = softplus(dtin @ W_dt + b_dt)  (K=64, 1 iter)
  k_gemm_bt<2><<<dim3(16, 32), 256, 0, stream>>>(dtin, WdtT, nullptr, nullptr, dtb, b_dt, 4096, 2048, 64);
  // 7-9. chunked selective scan (TC=64)
  k_scan_part<<<dim3(8, NCH, 4), 256, 0, stream>>>(dtb, xcs, xbc, A_log, Pb, Sb);
  k_scan_comb<<<4 * 16 * 2048 / 256, 256, 0, stream>>>(Pb, Sb);
  k_scan_y<<<dim3(8, NCH, 4), 256, 0, stream>>>(dtb, xcs, zsil, xbc, A_log, Pb, Dv, ysb);
  // 10. G4 split-K x2 -> f16 partials
  k_gemm_bt<5><<<dim3(8, 32, 2), 256, 0, stream>>>(ysb, WoutT, nullptr, ypH, nullptr, nullptr, 4096, 1024, 2048);
  // 11. residual + 2-plane f16 reduce + LN + LeakyReLU
  k_resid_ln<<<4096, 256, 0, stream>>>(x, ypH, gamma, beta, out);
}